// Round 8
// baseline (245.198 us; speedup 1.0000x reference)
//
#include <hip/hip_runtime.h>
#include <cstdint>

// Problem sizes (fixed by reference)
#define S_    2048
#define DM    1024
#define DH    4096
#define NTOK  8192     // B*S = 4*2048
#define WELEM 4194304  // 4096*1024 elements in each weight matrix
#define CT    8        // tokens per conv block

typedef int v4i __attribute__((ext_vector_type(4)));
typedef _Float16 half8 __attribute__((ext_vector_type(8)));
typedef char char8v __attribute__((ext_vector_type(8)));

// async global->LDS, 16B per lane, dest = wave-uniform base (+ lane*16 by HW)
#define GLOAD_LDS16(g, l)                                                   \
    __builtin_amdgcn_global_load_lds(                                       \
        (const __attribute__((address_space(1))) void*)(g),                 \
        (__attribute__((address_space(3))) void*)(l), 16, 0, 0)

// raw barrier (no implicit vmcnt(0) drain) + compiler memory fence
static __device__ __forceinline__ void sbar() {
    asm volatile("" ::: "memory");
    __builtin_amdgcn_s_barrier();
    asm volatile("" ::: "memory");
}
#define FENCE() asm volatile("" ::: "memory")
#define LGKM0() asm volatile("s_waitcnt lgkmcnt(0)" ::: "memory")
#define VMC0() asm volatile("s_waitcnt vmcnt(0)" ::: "memory")
#define VMC3() asm volatile("s_waitcnt vmcnt(3)" ::: "memory")
#define VMC4() asm volatile("s_waitcnt vmcnt(4)" ::: "memory")
#define VMC6() asm volatile("s_waitcnt vmcnt(6)" ::: "memory")

// ---------------------------------------------------------------------------
// Per-block partial sums of |w| in fp64, both matrices in one launch.
__global__ __launch_bounds__(256) void absmean_partial(const float4* __restrict__ wa,
                                                       const float4* __restrict__ wb,
                                                       double* __restrict__ partial) {
    __shared__ double red[256];
    const float4* w = (blockIdx.x < 1024) ? wa : wb;
    int base = (blockIdx.x & 1023) * 1024;  // in float4 units
    double s = 0.0;
#pragma unroll
    for (int k = 0; k < 4; ++k) {
        float4 v = w[base + (k << 8) + threadIdx.x];
        s += (double)fabsf(v.x) + (double)fabsf(v.y) +
             (double)fabsf(v.z) + (double)fabsf(v.w);
    }
    red[threadIdx.x] = s;
    __syncthreads();
    for (int off = 128; off > 0; off >>= 1) {
        if (threadIdx.x < off) red[threadIdx.x] += red[threadIdx.x + off];
        __syncthreads();
    }
    if (threadIdx.x == 0) partial[blockIdx.x] = red[0];
}

// Deterministic tree-sum of partials; scale = 1/clip(mean,1e-5) fp32.
__global__ __launch_bounds__(256) void finalize_scales(const double* __restrict__ part,
                                                       float* __restrict__ sc) {
    __shared__ double red[1024];
#pragma unroll 1
    for (int m = 0; m < 2; ++m) {
        const double* p = part + m * 1024;
        __syncthreads();
#pragma unroll
        for (int k = 0; k < 4; ++k) red[(k << 8) + threadIdx.x] = p[(k << 8) + threadIdx.x];
        __syncthreads();
        double s = red[threadIdx.x] + red[threadIdx.x + 256] +
                   red[threadIdx.x + 512] + red[threadIdx.x + 768];
        __syncthreads();
        red[threadIdx.x] = s;
        __syncthreads();
        for (int off = 128; off > 0; off >>= 1) {
            if (threadIdx.x < off) red[threadIdx.x] += red[threadIdx.x + off];
            __syncthreads();
        }
        if (threadIdx.x == 0) {
            double mean = red[0] / (double)WELEM;
            float mf = fmaxf((float)mean, 1e-5f);
            float scale = 1.0f / mf;
            sc[2 * m]     = scale;
            sc[2 * m + 1] = 1.0f / scale;
        }
    }
}

// One launch: blocks [0,8192) ternary-quantize w1/w2; [8192,16384) int8-quantize x.
__global__ __launch_bounds__(256) void quant_all(const float4* __restrict__ w1,
                                                 const float4* __restrict__ w2,
                                                 const float4* __restrict__ x,
                                                 char4* __restrict__ qw1,
                                                 char4* __restrict__ qw2,
                                                 char4* __restrict__ qx,
                                                 float* __restrict__ dqx,
                                                 const float* __restrict__ sc) {
    __shared__ float red[256];
    if (blockIdx.x < 8192) {
        bool second = blockIdx.x >= 4096;
        const float4* w = second ? w2 : w1;
        char4* q = second ? qw2 : qw1;
        float scale = sc[second ? 2 : 0];
        int i = (blockIdx.x & 4095) * 256 + threadIdx.x;
        float4 v = w[i];
        char4 o;
        o.x = (signed char)(int)fminf(fmaxf(rintf(v.x * scale), -1.f), 1.f);
        o.y = (signed char)(int)fminf(fmaxf(rintf(v.y * scale), -1.f), 1.f);
        o.z = (signed char)(int)fminf(fmaxf(rintf(v.z * scale), -1.f), 1.f);
        o.w = (signed char)(int)fminf(fmaxf(rintf(v.w * scale), -1.f), 1.f);
        q[i] = o;
    } else {
        int t = blockIdx.x - 8192;
        float4 v = x[(size_t)t * 256 + threadIdx.x];
        float mx = fmaxf(fmaxf(fabsf(v.x), fabsf(v.y)), fmaxf(fabsf(v.z), fabsf(v.w)));
        red[threadIdx.x] = mx;
        __syncthreads();
        for (int off = 128; off > 0; off >>= 1) {
            if (threadIdx.x < off) red[threadIdx.x] = fmaxf(red[threadIdx.x], red[threadIdx.x + off]);
            __syncthreads();
        }
        float scale = 127.0f / fmaxf(red[0], 1e-5f);
        // |v|*scale <= 127 by construction -> clamps redundant
        char4 o;
        o.x = (signed char)(int)rintf(v.x * scale);
        o.y = (signed char)(int)rintf(v.y * scale);
        o.z = (signed char)(int)rintf(v.z * scale);
        o.w = (signed char)(int)rintf(v.w * scale);
        qx[(size_t)t * 256 + threadIdx.x] = o;
        if (threadIdx.x == 0) dqx[t] = 1.0f / scale;
    }
}

// Fused depthwise conv3 (+bias) + SiLU + per-token int8 quant over DH=4096.
// SiLU via v_exp_f32/v_rcp_f32; quant clamps dropped (|v*scale| <= 127 by
// construction of scale).
__global__ __launch_bounds__(512) void conv_silu_quant(const half8* __restrict__ h,
                                                       const float4* __restrict__ cwv,
                                                       const float4* __restrict__ cbv,
                                                       char8v* __restrict__ q,
                                                       float* __restrict__ dq) {
    __shared__ float red[2][8];
    const int tid = threadIdx.x;
    const int t0 = blockIdx.x * CT;
    const int s0 = t0 & (S_ - 1);      // CT | S_, block never straddles batches

    float wc[24], bs[8];
    {
        float4 tmp;
#pragma unroll
        for (int i = 0; i < 6; ++i) {
            tmp = cwv[tid * 6 + i];
            wc[4 * i] = tmp.x; wc[4 * i + 1] = tmp.y; wc[4 * i + 2] = tmp.z; wc[4 * i + 3] = tmp.w;
        }
        tmp = cbv[tid * 2];     bs[0] = tmp.x; bs[1] = tmp.y; bs[2] = tmp.z; bs[3] = tmp.w;
        tmp = cbv[tid * 2 + 1]; bs[4] = tmp.x; bs[5] = tmp.y; bs[6] = tmp.z; bs[7] = tmp.w;
    }

    auto ldrow = [&](int t, bool valid, float* dst) {
        if (valid) {
            half8 raw = h[(size_t)t * 512 + tid];
#pragma unroll
            for (int e = 0; e < 8; ++e) dst[e] = (float)raw[e];
        } else {
#pragma unroll
            for (int e = 0; e < 8; ++e) dst[e] = 0.f;
        }
    };

    float pv[8], cu[8], nx[8], pf[8];
    ldrow(t0 - 1, s0 > 0, pv);
    ldrow(t0, true, cu);
    ldrow(t0 + 1, true, nx);

#pragma unroll
    for (int i = 0; i < CT; ++i) {
        const int t = t0 + i;
        ldrow(t + 2, (s0 + i + 2) < S_, pf);

        float v[8];
        float mx = 0.f;
#pragma unroll
        for (int e = 0; e < 8; ++e) {
            float y = wc[3 * e] * pv[e] + wc[3 * e + 1] * cu[e] + wc[3 * e + 2] * nx[e] + bs[e];
            // silu(y) = y * sigmoid(y) = y * rcp(1 + 2^(-y*log2e))
            float ex = __builtin_amdgcn_exp2f(-1.44269504088896f * y);
            float r  = y * __builtin_amdgcn_rcpf(1.0f + ex);
            v[e] = r;
            mx = fmaxf(mx, fabsf(r));
        }
#pragma unroll
        for (int off = 32; off > 0; off >>= 1)
            mx = fmaxf(mx, __shfl_down(mx, off, 64));
        if ((tid & 63) == 0) red[i & 1][tid >> 6] = mx;
        __syncthreads();
        float rmax = red[i & 1][0];
#pragma unroll
        for (int w = 1; w < 8; ++w) rmax = fmaxf(rmax, red[i & 1][w]);
        float scale = 127.0f / fmaxf(rmax, 1e-5f);
        char8v o;
#pragma unroll
        for (int e = 0; e < 8; ++e)
            o[e] = (signed char)(int)rintf(v[e] * scale);
        q[(size_t)t * 512 + tid] = o;
        if (tid == 0) dq[t] = 1.0f / scale;
#pragma unroll
        for (int e = 0; e < 8; ++e) { pv[e] = cu[e]; cu[e] = nx[e]; nx[e] = pf[e]; }
    }
}

// ---------------------------------------------------------------------------
// GEMM1 round 8: B direct-to-register (AITER pattern), A-only LDS.
// Diagnosis (r3-r7): overhead ~4800 cyc per 128-K invariant across all
// barrier/phase granularities -- every byte flowed through barrier-coupled
// LDS machinery, and i8 (2xK/instr) has half bf16's MFMA cycles to cover it.
// Fix: decouple B entirely. B frags load global->REGISTER per wave (L2-hot:
// 256KB slab/block, reused by 32 M-blocks), double-buffered, guarded only by
// per-wave counted vmcnt -- no barrier coupling. Only A stays in LDS:
// ring-4 x 16KB = 64KB -> 2 blocks/CU (4 waves/SIMD, cross-block TLP).
//
// BM=BN=256, BK=64, 8 waves 2(M)x4(N), wave-tile 128x64, acc[8][4].
// Per tile ONE region, ONE barrier, 32-MFMA cluster:
//   { 8x ds_read af | 4x gload B(t+1)->regs | 2x DMA A(t+2) }   (6 VMEM ops)
//   lgkm0 ; vmcnt(6) ; prio1 ; 32 MFMA ; prio0 ; s_barrier
// vmcnt region-count logic: each tile region issues exactly 6 VMEM ops, so
// vmcnt(6) retires ALL prior regions (B(t), A(t+1) and older) regardless of
// compiler ordering inside the region. Prologue is split into two fenced
// regions {A(0),A(1)} | {B(0)} so vmcnt(4) provably retires A(0)+A(1).
// Tail: vmcnt 6 -> 4 (no A(t+2)) -> 0 (last tile, epilogue follows).
// A-ring recycle (distance 4, 1 barrier/tile): stage(t+2) overwrites buf
// read at t-2, whose reads retired before the t-2 barrier in every wave.
//
// A swizzle (64B rows, verified r2-r7): phys_chunk = chunk ^ ((row>>1)&3),
// involution on staging source + ds_read. B needs no swizzle (registers).
__global__ __launch_bounds__(512, 2)
void gemm1_bdir(const int8_t* __restrict__ A, const int8_t* __restrict__ Bm,
                _Float16* __restrict__ C, const float* __restrict__ rowdq,
                const float* __restrict__ sc, int slot, int N, int K) {
    __shared__ __align__(16) int8_t lds[4][16384];   // A ring-4
    const int tid  = threadIdx.x;
    const int lane = tid & 63;
    const int wave = tid >> 6;

    // XCD-chunked bijective swizzle (grid 512, multiple of 8)
    const int nwg = gridDim.x * gridDim.y;
    int flat = blockIdx.y * gridDim.x + blockIdx.x;
    flat = (flat & 7) * (nwg >> 3) + (flat >> 3);
    const int bx = flat % gridDim.x;
    const int by = flat / gridDim.x;
    const int mbase = by << 8;               // BM=256
    const int nbase = bx << 8;               // BN=256
    const int NT = K >> 6;                   // 16 (even; unroll-by-2 below)

    const int wm = wave >> 2;                // 0..1  (128-row half)
    const int wn = wave & 3;                 // 0..3  (64-col quarter)

    // ---- A staging (inverse swizzle on global source); wave w: rows [32w,32w+32)
    const int srow = lane >> 2;                               // 0..15 in 1KB unit
    const int csrc = (((lane & 3) ^ ((lane >> 3) & 3)) << 4); // logical 16B chunk
    const int8_t* Ag = A + (size_t)(mbase + wave * 32 + srow) * K + csrc;

    auto stageA = [&](int b, int tt) {
        const size_t ko = (size_t)tt << 6;
        int8_t* d = &lds[b][wave << 11];
        GLOAD_LDS16(Ag + ko,                  d);
        GLOAD_LDS16(Ag + ko + (size_t)16 * K, d + 1024);
    };

    // ---- B direct-to-register (i8 16x16x64 B layout: n=lane&15, kchunk=lane>>4)
    const int8_t* Bg = Bm + (size_t)(nbase + wn * 64 + (lane & 15)) * K
                          + ((lane >> 4) << 4);
    auto loadB = [&](v4i (&bf)[4], int tt) {
        const size_t ko = (size_t)tt << 6;
#pragma unroll
        for (int j = 0; j < 4; ++j)
            bf[j] = *reinterpret_cast<const v4i*>(Bg + ko + (size_t)(j * 16) * K);
    };

    // ---- A frag read offsets (row = lane&15, chunk = lane>>4, swizzled)
    const int fc   = (((lane >> 4) ^ ((lane >> 1) & 3)) << 4);
    const int aoff = ((wm * 128 + (lane & 15)) << 6) + fc;    // + i*1024, i=0..7

    v4i acc[8][4] = {};
    v4i bf0[4], bf1[4];

    // prologue: region P1 {A(0), A(1)} | fence | region P2 {B(0)} | vmcnt(4)
    stageA(0, 0);
    stageA(1, 1);
    FENCE();
    loadB(bf0, 0);
    VMC4();            // retires P1 (A(0),A(1)); leaves B(0) in flight
    sbar();

    // tile body: bc = current B regs, bn = next (static names -- rule #20)
    auto tile = [&](int t, v4i (&bc)[4], v4i (&bn)[4]) {
        const int8_t* base = &lds[t & 3][0];
        v4i af[8];
#pragma unroll
        for (int i = 0; i < 8; ++i)
            af[i] = *reinterpret_cast<const v4i*>(base + aoff + (i << 10));
        if (t + 1 < NT) loadB(bn, t + 1);
        if (t + 2 < NT) stageA((t + 2) & 3, t + 2);
        LGKM0();
        if (t + 2 < NT)      VMC6();   // retire B(t), A(t+1) and older
        else if (t + 1 < NT) VMC4();
        else                 VMC0();
        __builtin_amdgcn_s_setprio(1);
#pragma unroll
        for (int i = 0; i < 8; ++i)
#pragma unroll
            for (int j = 0; j < 4; ++j)
                acc[i][j] = __builtin_amdgcn_mfma_i32_16x16x64_i8(af[i], bc[j], acc[i][j], 0, 0, 0);
        __builtin_amdgcn_s_setprio(0);
        sbar();
    };

    for (int t = 0; t < NT; t += 2) {   // NT even
        tile(t,     bf0, bf1);
        tile(t + 1, bf1, bf0);
    }

    // ---------------- epilogue ----------------
    const float wdq = sc[slot];
    const int quad = lane >> 4;
    const int col  = lane & 15;
#pragma unroll
    for (int i = 0; i < 8; ++i) {
#pragma unroll
        for (int r = 0; r < 4; ++r) {
            int m = mbase + (wm << 7) + (i << 4) + (quad << 2) + r;  // row=(lane>>4)*4+reg
            float rs = rowdq[m] * wdq;
#pragma unroll
            for (int j = 0; j < 4; ++j) {
                int n = nbase + (wn << 6) + (j << 4) + col;          // col=lane&15
                C[(size_t)m * N + n] = (_Float16)((float)acc[i][j][r] * rs);
            }
        }
    }
}

// ---------------------------------------------------------------------------
// GEMM2 kernel (grid-constrained by N=1024): BM=128/BN=128, 4 waves, BK=64,
// 3-deep ring, one barrier per tile, counted vmcnt. Unchanged from r3.
template <int BM, int WAVES, typename OutT>
__global__ __launch_bounds__(WAVES * 64, (BM == 256) ? 4 : 3)
void gemm_i8_bk64(const int8_t* __restrict__ A, const int8_t* __restrict__ Bm,
                  OutT* __restrict__ C, const float* __restrict__ rowdq,
                  const float* __restrict__ sc, int slot, int N, int K) {
    constexpr int BN = 128;
    constexpr int ABYTES = BM * 64;           // A bytes per ring buffer
    constexpr int BUF = (BM + BN) * 64;       // bytes per ring buffer
    constexpr int ALOADS = BM / 16 / WAVES;   // per-wave 1KB A loads per tile
    constexpr int BLOADS = BN / 16 / WAVES;   // per-wave 1KB B loads per tile
    constexpr int L = ALOADS + BLOADS;        // per-wave loads per tile

    __shared__ __align__(16) int8_t lds[3][BUF];
    const int tid  = threadIdx.x;
    const int lane = tid & 63;
    const int wave = tid >> 6;

    // XCD-chunked bijective swizzle (grid is a multiple of 8)
    const int nwg = gridDim.x * gridDim.y;
    int flat = blockIdx.y * gridDim.x + blockIdx.x;
    flat = (flat & 7) * (nwg >> 3) + (flat >> 3);
    const int bx = flat % gridDim.x;
    const int by = flat / gridDim.x;
    const int mbase = by * BM;
    const int nbase = bx << 7;
    const int NT = K >> 6;

    const int wm = wave >> 1;                 // m 64-row slab
    const int wn = wave & 1;                  // n 64-col half

    // ---- staging source addressing (inverse swizzle on global side)
    const int srow = lane >> 2;                               // row within 1KB load
    const int csrc = (((lane & 3) ^ ((lane >> 3) & 3)) << 4); // logical 16B chunk
    const int8_t* Ag = A  + (size_t)(mbase + wave * (ALOADS * 16) + srow) * K + csrc;
    const int8_t* Bg = Bm + (size_t)(nbase + wave * (BLOADS * 16) + srow) * K + csrc;

    auto stage = [&](int s, int tt) {
        const size_t ko = (size_t)tt << 6;
        int8_t* dA = &lds[s][(wave * ALOADS) << 10];
        int8_t* dB = &lds[s][ABYTES + ((wave * BLOADS) << 10)];
#pragma unroll
        for (int l = 0; l < ALOADS; ++l)
            GLOAD_LDS16(Ag + ko + (size_t)(l * 16) * K, dA + (l << 10));
#pragma unroll
        for (int l = 0; l < BLOADS; ++l)
            GLOAD_LDS16(Bg + ko + (size_t)(l * 16) * K, dB + (l << 10));
    };

    // ---- frag read offsets (i8 16x16x64: row = lane&15, chunk = lane>>4)
    const int fc   = (((lane >> 4) ^ ((lane >> 1) & 3)) << 4);  // swizzled chunk
    const int aoff = ((wm * 64 + (lane & 15)) << 6) + fc;       // + i*1024
    const int boff = ABYTES + ((wn * 64 + (lane & 15)) << 6) + fc;

    v4i acc[4][4] = {};

    // prologue: 2 tiles in flight; wait tile 0 (counted), cross-wave via barrier
    stage(0, 0);
    stage(1, 1);
    if constexpr (L == 3) VMC3(); else VMC4();
    sbar();

    int sb = 0;
    for (int t = 0; t < NT; ++t) {
        const int8_t* base = &lds[sb][0];
        v4i af[4], bf[4];
#pragma unroll
        for (int i = 0; i < 4; ++i)
            af[i] = *reinterpret_cast<const v4i*>(base + aoff + (i << 10));
#pragma unroll
        for (int j = 0; j < 4; ++j)
            bf[j] = *reinterpret_cast<const v4i*>(base + boff + (j << 10));
        int s2 = sb + 2; if (s2 >= 3) s2 -= 3;
        if (t + 2 < NT) stage(s2, t + 2);

        __builtin_amdgcn_s_setprio(1);
#pragma unroll
        for (int i = 0; i < 4; ++i)
#pragma unroll
            for (int j = 0; j < 4; ++j)
                acc[i][j] = __builtin_amdgcn_mfma_i32_16x16x64_i8(af[i], bf[j], acc[i][j], 0, 0, 0);
        __builtin_amdgcn_s_setprio(0);

        if (t + 2 < NT)      { if constexpr (L == 3) VMC3(); else VMC4(); }
        else if (t + 1 < NT) VMC0();
        sbar();
        if (++sb == 3) sb = 0;
    }

    // ---------------- epilogue ----------------
    const float wdq = sc[slot];
    const int quad = lane >> 4;
    const int col  = lane & 15;
#pragma unroll
    for (int i = 0; i < 4; ++i) {
#pragma unroll
        for (int r = 0; r < 4; ++r) {
            int m = mbase + (wm << 6) + (i << 4) + (quad << 2) + r;  // row=(lane>>4)*4+reg
            float rs = rowdq[m] * wdq;
#pragma unroll
            for (int j = 0; j < 4; ++j) {
                int n = nbase + (wn << 6) + (j << 4) + col;          // col=lane&15
                C[(size_t)m * N + n] = (OutT)((float)acc[i][j][r] * rs);
            }
        }
    }
}

// ---------------------------------------------------------------------------
extern "C" void kernel_launch(void* const* d_in, const int* in_sizes, int n_in,
                              void* d_out, int out_size, void* d_ws, size_t ws_size,
                              hipStream_t stream) {
    const float* x  = (const float*)d_in[0];  // [4,2048,1024]
    const float* w1 = (const float*)d_in[1];  // [4096,1024]
    const float* cw = (const float*)d_in[2];  // [4096,1,3]
    const float* cb = (const float*)d_in[3];  // [4096]
    const float* w2 = (const float*)d_in[4];  // [1024,4096]
    float* out = (float*)d_out;               // [4,2048,1024]
    char* ws = (char*)d_ws;

    // Workspace layout (16B-aligned)
    double* part  = (double*)(ws + 0);          // 2048 doubles
    float*  sc    = (float*)(ws + 16384);       // {scale_w1, dq_w1, scale_w2, dq_w2}
    float*  dqx   = (float*)(ws + 16640);       // 8192 floats
    float*  dqh   = (float*)(ws + 49408);       // 8192 floats
    int8_t* qw1   = (int8_t*)(ws + 82176);      // 4 MB
    int8_t* qw2   = (int8_t*)(ws + 4276480);    // 4 MB
    int8_t* qx    = (int8_t*)(ws + 8470784);    // 8 MB
    int8_t* qh    = (int8_t*)(ws + 16859392);   // 32 MB
    _Float16* h   = (_Float16*)(ws + 50413824); // 64 MB (fp16)

    absmean_partial<<<2048, 256, 0, stream>>>((const float4*)w1, (const float4*)w2, part);
    finalize_scales<<<1, 256, 0, stream>>>(part, sc);
    quant_all<<<16384, 256, 0, stream>>>((const float4*)w1, (const float4*)w2,
                                         (const float4*)x, (char4*)qw1, (char4*)qw2,
                                         (char4*)qx, dqx, sc);

    // GEMM1: M=8192, N=4096, K=1024 -> h (fp16); 512 blocks, 2 blocks/CU
    dim3 g1(DH / 256, NTOK / 256);
    gemm1_bdir<<<g1, 512, 0, stream>>>(qx, qw1, h, dqx, sc, 1, DH, DM);

    conv_silu_quant<<<NTOK / CT, 512, 0, stream>>>((const half8*)h, (const float4*)cw,
                                                   (const float4*)cb, (char8v*)qh, dqh);

    // GEMM2: M=8192, N=1024, K=4096 -> out (fp32); 512 blocks
    dim3 g2(DM / 128, NTOK / 128);
    gemm_i8_bk64<128, 4, float><<<g2, 256, 0, stream>>>(qh, qw2, out, dqh, sc, 3, DM, DH);
}

// Round 9
// 241.455 us; speedup vs baseline: 1.0155x; 1.0155x over previous
//
#include <hip/hip_runtime.h>
#include <cstdint>

// Problem sizes (fixed by reference)
#define S_    2048
#define DM    1024
#define DH    4096
#define NTOK  8192     // B*S = 4*2048
#define WELEM 4194304  // 4096*1024 elements in each weight matrix
#define CT    8        // tokens per conv block

typedef int v4i __attribute__((ext_vector_type(4)));
typedef _Float16 half8 __attribute__((ext_vector_type(8)));
typedef char char8v __attribute__((ext_vector_type(8)));

// async global->LDS, 16B per lane, dest = wave-uniform base (+ lane*16 by HW)
#define GLOAD_LDS16(g, l)                                                   \
    __builtin_amdgcn_global_load_lds(                                       \
        (const __attribute__((address_space(1))) void*)(g),                 \
        (__attribute__((address_space(3))) void*)(l), 16, 0, 0)

// raw barrier (no implicit vmcnt(0) drain) + compiler memory fence
static __device__ __forceinline__ void sbar() {
    asm volatile("" ::: "memory");
    __builtin_amdgcn_s_barrier();
    asm volatile("" ::: "memory");
}
#define VMC0() asm volatile("s_waitcnt vmcnt(0)" ::: "memory")
#define VMC3() asm volatile("s_waitcnt vmcnt(3)" ::: "memory")
#define VMC4() asm volatile("s_waitcnt vmcnt(4)" ::: "memory")

// ---------------------------------------------------------------------------
// Per-block partial sums of |w| in fp64, both matrices in one launch.
__global__ __launch_bounds__(256) void absmean_partial(const float4* __restrict__ wa,
                                                       const float4* __restrict__ wb,
                                                       double* __restrict__ partial) {
    __shared__ double red[256];
    const float4* w = (blockIdx.x < 1024) ? wa : wb;
    int base = (blockIdx.x & 1023) * 1024;  // in float4 units
    double s = 0.0;
#pragma unroll
    for (int k = 0; k < 4; ++k) {
        float4 v = w[base + (k << 8) + threadIdx.x];
        s += (double)fabsf(v.x) + (double)fabsf(v.y) +
             (double)fabsf(v.z) + (double)fabsf(v.w);
    }
    red[threadIdx.x] = s;
    __syncthreads();
    for (int off = 128; off > 0; off >>= 1) {
        if (threadIdx.x < off) red[threadIdx.x] += red[threadIdx.x + off];
        __syncthreads();
    }
    if (threadIdx.x == 0) partial[blockIdx.x] = red[0];
}

// Deterministic tree-sum of partials; scale = 1/clip(mean,1e-5) fp32.
__global__ __launch_bounds__(256) void finalize_scales(const double* __restrict__ part,
                                                       float* __restrict__ sc) {
    __shared__ double red[1024];
#pragma unroll 1
    for (int m = 0; m < 2; ++m) {
        const double* p = part + m * 1024;
        __syncthreads();
#pragma unroll
        for (int k = 0; k < 4; ++k) red[(k << 8) + threadIdx.x] = p[(k << 8) + threadIdx.x];
        __syncthreads();
        double s = red[threadIdx.x] + red[threadIdx.x + 256] +
                   red[threadIdx.x + 512] + red[threadIdx.x + 768];
        __syncthreads();
        red[threadIdx.x] = s;
        __syncthreads();
        for (int off = 128; off > 0; off >>= 1) {
            if (threadIdx.x < off) red[threadIdx.x] += red[threadIdx.x + off];
            __syncthreads();
        }
        if (threadIdx.x == 0) {
            double mean = red[0] / (double)WELEM;
            float mf = fmaxf((float)mean, 1e-5f);
            float scale = 1.0f / mf;
            sc[2 * m]     = scale;
            sc[2 * m + 1] = 1.0f / scale;
        }
    }
}

// One launch: blocks [0,8192) ternary-quantize w1/w2; [8192,16384) int8-quantize x.
__global__ __launch_bounds__(256) void quant_all(const float4* __restrict__ w1,
                                                 const float4* __restrict__ w2,
                                                 const float4* __restrict__ x,
                                                 char4* __restrict__ qw1,
                                                 char4* __restrict__ qw2,
                                                 char4* __restrict__ qx,
                                                 float* __restrict__ dqx,
                                                 const float* __restrict__ sc) {
    __shared__ float red[256];
    if (blockIdx.x < 8192) {
        bool second = blockIdx.x >= 4096;
        const float4* w = second ? w2 : w1;
        char4* q = second ? qw2 : qw1;
        float scale = sc[second ? 2 : 0];
        int i = (blockIdx.x & 4095) * 256 + threadIdx.x;
        float4 v = w[i];
        char4 o;
        o.x = (signed char)(int)fminf(fmaxf(rintf(v.x * scale), -1.f), 1.f);
        o.y = (signed char)(int)fminf(fmaxf(rintf(v.y * scale), -1.f), 1.f);
        o.z = (signed char)(int)fminf(fmaxf(rintf(v.z * scale), -1.f), 1.f);
        o.w = (signed char)(int)fminf(fmaxf(rintf(v.w * scale), -1.f), 1.f);
        q[i] = o;
    } else {
        int t = blockIdx.x - 8192;
        float4 v = x[(size_t)t * 256 + threadIdx.x];
        float mx = fmaxf(fmaxf(fabsf(v.x), fabsf(v.y)), fmaxf(fabsf(v.z), fabsf(v.w)));
        red[threadIdx.x] = mx;
        __syncthreads();
        for (int off = 128; off > 0; off >>= 1) {
            if (threadIdx.x < off) red[threadIdx.x] = fmaxf(red[threadIdx.x], red[threadIdx.x + off]);
            __syncthreads();
        }
        float scale = 127.0f / fmaxf(red[0], 1e-5f);
        // |v|*scale <= 127 by construction -> clamps redundant
        char4 o;
        o.x = (signed char)(int)rintf(v.x * scale);
        o.y = (signed char)(int)rintf(v.y * scale);
        o.z = (signed char)(int)rintf(v.z * scale);
        o.w = (signed char)(int)rintf(v.w * scale);
        qx[(size_t)t * 256 + threadIdx.x] = o;
        if (threadIdx.x == 0) dqx[t] = 1.0f / scale;
    }
}

// Fused depthwise conv3 (+bias) + SiLU + per-token int8 quant over DH=4096.
// SiLU via v_exp_f32/v_rcp_f32; quant clamps dropped (|v*scale| <= 127 by
// construction of scale).
__global__ __launch_bounds__(512) void conv_silu_quant(const half8* __restrict__ h,
                                                       const float4* __restrict__ cwv,
                                                       const float4* __restrict__ cbv,
                                                       char8v* __restrict__ q,
                                                       float* __restrict__ dq) {
    __shared__ float red[2][8];
    const int tid = threadIdx.x;
    const int t0 = blockIdx.x * CT;
    const int s0 = t0 & (S_ - 1);      // CT | S_, block never straddles batches

    float wc[24], bs[8];
    {
        float4 tmp;
#pragma unroll
        for (int i = 0; i < 6; ++i) {
            tmp = cwv[tid * 6 + i];
            wc[4 * i] = tmp.x; wc[4 * i + 1] = tmp.y; wc[4 * i + 2] = tmp.z; wc[4 * i + 3] = tmp.w;
        }
        tmp = cbv[tid * 2];     bs[0] = tmp.x; bs[1] = tmp.y; bs[2] = tmp.z; bs[3] = tmp.w;
        tmp = cbv[tid * 2 + 1]; bs[4] = tmp.x; bs[5] = tmp.y; bs[6] = tmp.z; bs[7] = tmp.w;
    }

    auto ldrow = [&](int t, bool valid, float* dst) {
        if (valid) {
            half8 raw = h[(size_t)t * 512 + tid];
#pragma unroll
            for (int e = 0; e < 8; ++e) dst[e] = (float)raw[e];
        } else {
#pragma unroll
            for (int e = 0; e < 8; ++e) dst[e] = 0.f;
        }
    };

    float pv[8], cu[8], nx[8], pf[8];
    ldrow(t0 - 1, s0 > 0, pv);
    ldrow(t0, true, cu);
    ldrow(t0 + 1, true, nx);

#pragma unroll
    for (int i = 0; i < CT; ++i) {
        const int t = t0 + i;
        ldrow(t + 2, (s0 + i + 2) < S_, pf);

        float v[8];
        float mx = 0.f;
#pragma unroll
        for (int e = 0; e < 8; ++e) {
            float y = wc[3 * e] * pv[e] + wc[3 * e + 1] * cu[e] + wc[3 * e + 2] * nx[e] + bs[e];
            // silu(y) = y * sigmoid(y) = y * rcp(1 + 2^(-y*log2e))
            float ex = __builtin_amdgcn_exp2f(-1.44269504088896f * y);
            float r  = y * __builtin_amdgcn_rcpf(1.0f + ex);
            v[e] = r;
            mx = fmaxf(mx, fabsf(r));
        }
#pragma unroll
        for (int off = 32; off > 0; off >>= 1)
            mx = fmaxf(mx, __shfl_down(mx, off, 64));
        if ((tid & 63) == 0) red[i & 1][tid >> 6] = mx;
        __syncthreads();
        float rmax = red[i & 1][0];
#pragma unroll
        for (int w = 1; w < 8; ++w) rmax = fmaxf(rmax, red[i & 1][w]);
        float scale = 127.0f / fmaxf(rmax, 1e-5f);
        char8v o;
#pragma unroll
        for (int e = 0; e < 8; ++e)
            o[e] = (signed char)(int)rintf(v[e] * scale);
        q[(size_t)t * 512 + tid] = o;
        if (tid == 0) dq[t] = 1.0f / scale;
#pragma unroll
        for (int e = 0; e < 8; ++e) { pv[e] = cu[e]; cu[e] = nx[e]; nx[e] = pf[e]; }
    }
}

// ---------------------------------------------------------------------------
// int8 x ternary GEMM, BK=64, one barrier per K-tile, 3-deep ring, counted
// vmcnt:  C[m,n] = (sum_k A[m,k]*B[n,k]) * rowdq[m] * sc[slot]
//
// Round 9: BOTH GEMMs use the <128,4> instance (48KB LDS -> 3 blocks/CU,
// 3 waves/SIMD, wave-tile 64x64 acc[4][4] ~130 regs). Evidence: every
// 2-waves/SIMD structure tried for GEMM1 (r3 bk64<256,8>, r5 w128, r6
// fine-phase, r7 BK=128, r8 B-direct) landed 49-63 us, while GEMM2 running
// THIS config never once entered the top-5 (always < the ~48.5 cut) with
// identical FLOPs. Register arithmetic says 128x64 wave tiles (acc 128 regs)
// structurally exclude 3 waves/SIMD (512/3=170 < ~190 needed); 64x64 fits.
//
// Protocol (single barrier per tile, counted vmcnt never 0 mid-loop):
//   tile t: ds_read frags(buf t%3) | stage(t+2 -> buf (t+2)%3) |
//           16 x mfma (compiler-inserted fine lgkmcnt) | vmcnt(3) | s_barrier
// Recycle safety: any wave past barrier(t) finished its MFMAs(t), hence its
// ds_reads(t) completed; stage(t+3) into buf t%3 is issued only after
// barrier(t). vmcnt(3) at barrier(t) retires tile t+1's loads (its own 3
// newest, tile t+2's, remain in flight); barrier makes that cross-wave safe.
//
// Swizzle (64B LDS rows): phys_chunk = chunk ^ ((row>>1)&3). Involution,
// applied on the global staging source (linear DMA dest) and on ds_read.
// 16-lane frag groups spread over all 8 bank-slot classes exactly 2x
// (2-way aliasing is free, m136). Verified conflict-free r2-r8.
template <int BM, int WAVES, typename OutT>
__global__ __launch_bounds__(WAVES * 64, (BM == 256) ? 4 : 3)
void gemm_i8_bk64(const int8_t* __restrict__ A, const int8_t* __restrict__ Bm,
                  OutT* __restrict__ C, const float* __restrict__ rowdq,
                  const float* __restrict__ sc, int slot, int N, int K) {
    constexpr int BN = 128;
    constexpr int ABYTES = BM * 64;           // A bytes per ring buffer
    constexpr int BUF = (BM + BN) * 64;       // bytes per ring buffer
    constexpr int ALOADS = BM / 16 / WAVES;   // per-wave 1KB A loads per tile
    constexpr int BLOADS = BN / 16 / WAVES;   // per-wave 1KB B loads per tile
    constexpr int L = ALOADS + BLOADS;        // per-wave loads per tile

    __shared__ __align__(16) int8_t lds[3][BUF];
    const int tid  = threadIdx.x;
    const int lane = tid & 63;
    const int wave = tid >> 6;

    // XCD-chunked bijective swizzle (grid is a multiple of 8)
    const int nwg = gridDim.x * gridDim.y;
    int flat = blockIdx.y * gridDim.x + blockIdx.x;
    flat = (flat & 7) * (nwg >> 3) + (flat >> 3);
    const int bx = flat % gridDim.x;
    const int by = flat / gridDim.x;
    const int mbase = by * BM;
    const int nbase = bx << 7;
    const int NT = K >> 6;

    const int wm = wave >> 1;                 // m 64-row slab
    const int wn = wave & 1;                  // n 64-col half

    // ---- staging source addressing (inverse swizzle on global side)
    const int srow = lane >> 2;                               // row within 1KB load
    const int csrc = (((lane & 3) ^ ((lane >> 3) & 3)) << 4); // logical 16B chunk
    const int8_t* Ag = A  + (size_t)(mbase + wave * (ALOADS * 16) + srow) * K + csrc;
    const int8_t* Bg = Bm + (size_t)(nbase + wave * (BLOADS * 16) + srow) * K + csrc;

    auto stage = [&](int s, int tt) {
        const size_t ko = (size_t)tt << 6;
        int8_t* dA = &lds[s][(wave * ALOADS) << 10];
        int8_t* dB = &lds[s][ABYTES + ((wave * BLOADS) << 10)];
#pragma unroll
        for (int l = 0; l < ALOADS; ++l)
            GLOAD_LDS16(Ag + ko + (size_t)(l * 16) * K, dA + (l << 10));
#pragma unroll
        for (int l = 0; l < BLOADS; ++l)
            GLOAD_LDS16(Bg + ko + (size_t)(l * 16) * K, dB + (l << 10));
    };

    // ---- frag read offsets (i8 16x16x64: row = lane&15, chunk = lane>>4)
    const int fc   = (((lane >> 4) ^ ((lane >> 1) & 3)) << 4);  // swizzled chunk
    const int aoff = ((wm * 64 + (lane & 15)) << 6) + fc;       // + i*1024
    const int boff = ABYTES + ((wn * 64 + (lane & 15)) << 6) + fc;

    v4i acc[4][4] = {};

    // prologue: 2 tiles in flight; wait tile 0 (counted), cross-wave via barrier
    stage(0, 0);
    stage(1, 1);
    if constexpr (L == 3) VMC3(); else VMC4();
    sbar();

    int sb = 0;
    for (int t = 0; t < NT; ++t) {
        const int8_t* base = &lds[sb][0];
        v4i af[4], bf[4];
#pragma unroll
        for (int i = 0; i < 4; ++i)
            af[i] = *reinterpret_cast<const v4i*>(base + aoff + (i << 10));
#pragma unroll
        for (int j = 0; j < 4; ++j)
            bf[j] = *reinterpret_cast<const v4i*>(base + boff + (j << 10));
        int s2 = sb + 2; if (s2 >= 3) s2 -= 3;
        if (t + 2 < NT) stage(s2, t + 2);

        __builtin_amdgcn_s_setprio(1);
#pragma unroll
        for (int i = 0; i < 4; ++i)
#pragma unroll
            for (int j = 0; j < 4; ++j)
                acc[i][j] = __builtin_amdgcn_mfma_i32_16x16x64_i8(af[i], bf[j], acc[i][j], 0, 0, 0);
        __builtin_amdgcn_s_setprio(0);

        if (t + 2 < NT)      { if constexpr (L == 3) VMC3(); else VMC4(); }
        else if (t + 1 < NT) VMC0();
        sbar();
        if (++sb == 3) sb = 0;
    }

    // ---------------- epilogue ----------------
    const float wdq = sc[slot];
    const int quad = lane >> 4;
    const int col  = lane & 15;
#pragma unroll
    for (int i = 0; i < 4; ++i) {
#pragma unroll
        for (int r = 0; r < 4; ++r) {
            int m = mbase + (wm << 6) + (i << 4) + (quad << 2) + r;  // row=(lane>>4)*4+reg
            float rs = rowdq[m] * wdq;
#pragma unroll
            for (int j = 0; j < 4; ++j) {
                int n = nbase + (wn << 6) + (j << 4) + col;          // col=lane&15
                C[(size_t)m * N + n] = (OutT)((float)acc[i][j][r] * rs);
            }
        }
    }
}

// ---------------------------------------------------------------------------
extern "C" void kernel_launch(void* const* d_in, const int* in_sizes, int n_in,
                              void* d_out, int out_size, void* d_ws, size_t ws_size,
                              hipStream_t stream) {
    const float* x  = (const float*)d_in[0];  // [4,2048,1024]
    const float* w1 = (const float*)d_in[1];  // [4096,1024]
    const float* cw = (const float*)d_in[2];  // [4096,1,3]
    const float* cb = (const float*)d_in[3];  // [4096]
    const float* w2 = (const float*)d_in[4];  // [1024,4096]
    float* out = (float*)d_out;               // [4,2048,1024]
    char* ws = (char*)d_ws;

    // Workspace layout (16B-aligned)
    double* part  = (double*)(ws + 0);          // 2048 doubles
    float*  sc    = (float*)(ws + 16384);       // {scale_w1, dq_w1, scale_w2, dq_w2}
    float*  dqx   = (float*)(ws + 16640);       // 8192 floats
    float*  dqh   = (float*)(ws + 49408);       // 8192 floats
    int8_t* qw1   = (int8_t*)(ws + 82176);      // 4 MB
    int8_t* qw2   = (int8_t*)(ws + 4276480);    // 4 MB
    int8_t* qx    = (int8_t*)(ws + 8470784);    // 8 MB
    int8_t* qh    = (int8_t*)(ws + 16859392);   // 32 MB
    _Float16* h   = (_Float16*)(ws + 50413824); // 64 MB (fp16)

    absmean_partial<<<2048, 256, 0, stream>>>((const float4*)w1, (const float4*)w2, part);
    finalize_scales<<<1, 256, 0, stream>>>(part, sc);
    quant_all<<<16384, 256, 0, stream>>>((const float4*)w1, (const float4*)w2,
                                         (const float4*)x, (char4*)qw1, (char4*)qw2,
                                         (char4*)qx, dqx, sc);

    // GEMM1: M=8192, N=4096, K=1024 -> h (fp16); 2048 blocks, 3 blocks/CU
    dim3 g1(DH / 128, NTOK / 128);
    gemm_i8_bk64<128, 4, _Float16><<<g1, 256, 0, stream>>>(qx, qw1, h, dqx, sc, 1, DH, DM);

    conv_silu_quant<<<NTOK / CT, 512, 0, stream>>>((const half8*)h, (const float4*)cw,
                                                   (const float4*)cb, (char8v*)qh, dqh);

    // GEMM2: M=8192, N=1024, K=4096 -> out (fp32); 512 blocks, 3 blocks/CU
    dim3 g2(DM / 128, NTOK / 128);
    gemm_i8_bk64<128, 4, float><<<g2, 256, 0, stream>>>(qh, qw2, out, dqh, sc, 3, DM, DH);
}

// Round 10
// 234.218 us; speedup vs baseline: 1.0469x; 1.0309x over previous
//
#include <hip/hip_runtime.h>
#include <cstdint>

// Problem sizes (fixed by reference)
#define S_    2048
#define DM    1024
#define DH    4096
#define NTOK  8192     // B*S = 4*2048
#define WELEM 4194304  // 4096*1024 elements in each weight matrix
#define CT    8        // tokens per conv block

typedef int v4i __attribute__((ext_vector_type(4)));
typedef _Float16 half8 __attribute__((ext_vector_type(8)));
typedef char char8v __attribute__((ext_vector_type(8)));

// async global->LDS, 16B per lane, dest = wave-uniform base (+ lane*16 by HW)
#define GLOAD_LDS16(g, l)                                                   \
    __builtin_amdgcn_global_load_lds(                                       \
        (const __attribute__((address_space(1))) void*)(g),                 \
        (__attribute__((address_space(3))) void*)(l), 16, 0, 0)

// raw barrier (no implicit vmcnt(0) drain) + compiler memory fence
static __device__ __forceinline__ void sbar() {
    asm volatile("" ::: "memory");
    __builtin_amdgcn_s_barrier();
    asm volatile("" ::: "memory");
}
#define VMC0() asm volatile("s_waitcnt vmcnt(0)" ::: "memory")
#define VMC3() asm volatile("s_waitcnt vmcnt(3)" ::: "memory")
#define VMC4() asm volatile("s_waitcnt vmcnt(4)" ::: "memory")
#define VMC6() asm volatile("s_waitcnt vmcnt(6)" ::: "memory")

// ---------------------------------------------------------------------------
// Per-block partial sums of |w| in fp64, both matrices in one launch.
__global__ __launch_bounds__(256) void absmean_partial(const float4* __restrict__ wa,
                                                       const float4* __restrict__ wb,
                                                       double* __restrict__ partial) {
    __shared__ double red[256];
    const float4* w = (blockIdx.x < 1024) ? wa : wb;
    int base = (blockIdx.x & 1023) * 1024;  // in float4 units
    double s = 0.0;
#pragma unroll
    for (int k = 0; k < 4; ++k) {
        float4 v = w[base + (k << 8) + threadIdx.x];
        s += (double)fabsf(v.x) + (double)fabsf(v.y) +
             (double)fabsf(v.z) + (double)fabsf(v.w);
    }
    red[threadIdx.x] = s;
    __syncthreads();
    for (int off = 128; off > 0; off >>= 1) {
        if (threadIdx.x < off) red[threadIdx.x] += red[threadIdx.x + off];
        __syncthreads();
    }
    if (threadIdx.x == 0) partial[blockIdx.x] = red[0];
}

// ---------------------------------------------------------------------------
// Deterministic recompute of {scale, 1/scale} from the 1024 fp64 partials of
// matrix m (0=w1, 1=w2). REQUIRES 256-thread blocks. Every calling block
// performs the identical IEEE op sequence (same adds, same tree as the old
// finalize_scales kernel) -> bit-identical scale in every consumer, which
// replaces the dedicated 1-block finalize launch (pure latency) entirely.
__device__ __forceinline__ float2 scale_pair(const double* __restrict__ part, int m,
                                             double* red) {
    const double* p = part + (m << 10);
    const int t = threadIdx.x;
    double s = p[t] + p[t + 256] + p[t + 512] + p[t + 768];
    red[t] = s;
    __syncthreads();
    for (int off = 128; off > 0; off >>= 1) {
        if (t < off) red[t] += red[t + off];
        __syncthreads();
    }
    double mean = red[0] / (double)WELEM;
    float mf = fmaxf((float)mean, 1e-5f);
    float scale = 1.0f / mf;
    float2 r; r.x = scale; r.y = 1.0f / scale;
    return r;
}

// One launch: blocks [0,8192) ternary-quantize w1/w2; [8192,16384) int8-quantize x.
__global__ __launch_bounds__(256) void quant_all(const float4* __restrict__ w1,
                                                 const float4* __restrict__ w2,
                                                 const float4* __restrict__ x,
                                                 char4* __restrict__ qw1,
                                                 char4* __restrict__ qw2,
                                                 char4* __restrict__ qx,
                                                 float* __restrict__ dqx,
                                                 const double* __restrict__ part) {
    __shared__ double redd[256];
    __shared__ float  redf[256];
    if (blockIdx.x < 8192) {
        bool second = blockIdx.x >= 4096;
        const float4* w = second ? w2 : w1;
        char4* q = second ? qw2 : qw1;
        float scale = scale_pair(part, second ? 1 : 0, redd).x;
        int i = (blockIdx.x & 4095) * 256 + threadIdx.x;
        float4 v = w[i];
        char4 o;
        o.x = (signed char)(int)fminf(fmaxf(rintf(v.x * scale), -1.f), 1.f);
        o.y = (signed char)(int)fminf(fmaxf(rintf(v.y * scale), -1.f), 1.f);
        o.z = (signed char)(int)fminf(fmaxf(rintf(v.z * scale), -1.f), 1.f);
        o.w = (signed char)(int)fminf(fmaxf(rintf(v.w * scale), -1.f), 1.f);
        q[i] = o;
    } else {
        int t = blockIdx.x - 8192;
        float4 v = x[(size_t)t * 256 + threadIdx.x];
        float mx = fmaxf(fmaxf(fabsf(v.x), fabsf(v.y)), fmaxf(fabsf(v.z), fabsf(v.w)));
        redf[threadIdx.x] = mx;
        __syncthreads();
        for (int off = 128; off > 0; off >>= 1) {
            if (threadIdx.x < off) redf[threadIdx.x] = fmaxf(redf[threadIdx.x], redf[threadIdx.x + off]);
            __syncthreads();
        }
        float scale = 127.0f / fmaxf(redf[0], 1e-5f);
        // |v|*scale <= 127 by construction -> clamps redundant
        char4 o;
        o.x = (signed char)(int)rintf(v.x * scale);
        o.y = (signed char)(int)rintf(v.y * scale);
        o.z = (signed char)(int)rintf(v.z * scale);
        o.w = (signed char)(int)rintf(v.w * scale);
        qx[(size_t)t * 256 + threadIdx.x] = o;
        if (threadIdx.x == 0) dqx[t] = 1.0f / scale;
    }
}

// Fused depthwise conv3 (+bias) + SiLU + per-token int8 quant over DH=4096.
// SiLU via v_exp_f32/v_rcp_f32; quant clamps dropped (|v*scale| <= 127 by
// construction of scale).
__global__ __launch_bounds__(512) void conv_silu_quant(const half8* __restrict__ h,
                                                       const float4* __restrict__ cwv,
                                                       const float4* __restrict__ cbv,
                                                       char8v* __restrict__ q,
                                                       float* __restrict__ dq) {
    __shared__ float red[2][8];
    const int tid = threadIdx.x;
    const int t0 = blockIdx.x * CT;
    const int s0 = t0 & (S_ - 1);      // CT | S_, block never straddles batches

    float wc[24], bs[8];
    {
        float4 tmp;
#pragma unroll
        for (int i = 0; i < 6; ++i) {
            tmp = cwv[tid * 6 + i];
            wc[4 * i] = tmp.x; wc[4 * i + 1] = tmp.y; wc[4 * i + 2] = tmp.z; wc[4 * i + 3] = tmp.w;
        }
        tmp = cbv[tid * 2];     bs[0] = tmp.x; bs[1] = tmp.y; bs[2] = tmp.z; bs[3] = tmp.w;
        tmp = cbv[tid * 2 + 1]; bs[4] = tmp.x; bs[5] = tmp.y; bs[6] = tmp.z; bs[7] = tmp.w;
    }

    auto ldrow = [&](int t, bool valid, float* dst) {
        if (valid) {
            half8 raw = h[(size_t)t * 512 + tid];
#pragma unroll
            for (int e = 0; e < 8; ++e) dst[e] = (float)raw[e];
        } else {
#pragma unroll
            for (int e = 0; e < 8; ++e) dst[e] = 0.f;
        }
    };

    float pv[8], cu[8], nx[8], pf[8];
    ldrow(t0 - 1, s0 > 0, pv);
    ldrow(t0, true, cu);
    ldrow(t0 + 1, true, nx);

#pragma unroll
    for (int i = 0; i < CT; ++i) {
        const int t = t0 + i;
        ldrow(t + 2, (s0 + i + 2) < S_, pf);

        float v[8];
        float mx = 0.f;
#pragma unroll
        for (int e = 0; e < 8; ++e) {
            float y = wc[3 * e] * pv[e] + wc[3 * e + 1] * cu[e] + wc[3 * e + 2] * nx[e] + bs[e];
            // silu(y) = y * sigmoid(y) = y * rcp(1 + 2^(-y*log2e))
            float ex = __builtin_amdgcn_exp2f(-1.44269504088896f * y);
            float r  = y * __builtin_amdgcn_rcpf(1.0f + ex);
            v[e] = r;
            mx = fmaxf(mx, fabsf(r));
        }
#pragma unroll
        for (int off = 32; off > 0; off >>= 1)
            mx = fmaxf(mx, __shfl_down(mx, off, 64));
        if ((tid & 63) == 0) red[i & 1][tid >> 6] = mx;
        __syncthreads();
        float rmax = red[i & 1][0];
#pragma unroll
        for (int w = 1; w < 8; ++w) rmax = fmaxf(rmax, red[i & 1][w]);
        float scale = 127.0f / fmaxf(rmax, 1e-5f);
        char8v o;
#pragma unroll
        for (int e = 0; e < 8; ++e)
            o[e] = (signed char)(int)rintf(v[e] * scale);
        q[(size_t)t * 512 + tid] = o;
        if (tid == 0) dq[t] = 1.0f / scale;
#pragma unroll
        for (int e = 0; e < 8; ++e) { pv[e] = cu[e]; cu[e] = nx[e]; nx[e] = pf[e]; }
    }
}

// ---------------------------------------------------------------------------
// GEMM1 kernel (r5 config, best measured: 49.1 us): 256x128 block tile, BK=64,
// 4 waves as 2(M)x2(N), wave-tile 128x64, acc[8][4]. 3-deep LDS ring
// (3 x 24KB), __launch_bounds__(256,2): 256 regs/wave, no spill; 2 blocks/CU,
// each SIMD hosts waves from two different blocks (cross-block overlap).
//
// Protocol per K-tile (one barrier, counted vmcnt never 0 mid-loop):
//   bf[4]+af[0..3] ds_read | stage(t+2) | 16 mfma | af[4..7] ds_read |
//   16 mfma | vmcnt(6) | s_barrier
// Recycle safety: stage(t+2) overwrites the buffer last read at t-1; every
// wave's t-1 ds_reads retired before its t-1 MFMAs (register dependency),
// which precede barrier(t-1), which precedes stage(t+2).
// vmcnt(6): at the wait, 12 loads in flight (t+1's 6 + t+2's 6); retires
// t+1's. Barrier makes the per-wave guarantee cross-wave.
//
// Swizzle (64B LDS rows, verified conflict-free r2-r9): phys_chunk =
// chunk ^ ((row>>1)&3), involution on both staging source and ds_read.
template <typename OutT>
__global__ __launch_bounds__(256, 2)
void gemm_i8_w128(const int8_t* __restrict__ A, const int8_t* __restrict__ Bm,
                  OutT* __restrict__ C, const float* __restrict__ rowdq,
                  const double* __restrict__ part, int widx, int N, int K) {
    __shared__ __align__(16) int8_t lds[3][24576];   // [buf][A 16KB | B 8KB]
    __shared__ double sred[256];
    const int tid  = threadIdx.x;
    const int lane = tid & 63;
    const int wave = tid >> 6;

    // weight dequant scale, recomputed deterministically (replaces finalize)
    const float wdq = scale_pair(part, widx, sred).y;

    // XCD-chunked bijective swizzle (grid is a multiple of 8)
    const int nwg = gridDim.x * gridDim.y;
    int flat = blockIdx.y * gridDim.x + blockIdx.x;
    flat = (flat & 7) * (nwg >> 3) + (flat >> 3);
    const int bx = flat % gridDim.x;
    const int by = flat / gridDim.x;
    const int mbase = by << 8;               // BM=256
    const int nbase = bx << 7;               // BN=128
    const int NT = K >> 6;

    const int wm = wave >> 1;                // 0..1  (128-row half)
    const int wn = wave & 1;                 // 0..1  (64-col half)

    // ---- staging source addressing (inverse swizzle on global side)
    // wave w stages A rows [64w,64w+64) (4 x 1KB) and B rows [32w,32w+32) (2 x 1KB)
    const int srow = lane >> 2;                               // row within 1KB unit
    const int csrc = (((lane & 3) ^ ((lane >> 3) & 3)) << 4); // logical 16B chunk
    const int8_t* Ag = A  + (size_t)(mbase + wave * 64 + srow) * K + csrc;
    const int8_t* Bg = Bm + (size_t)(nbase + wave * 32 + srow) * K + csrc;

    auto stage = [&](int s, int tt) {
        const size_t ko = (size_t)tt << 6;
        int8_t* dA = &lds[s][wave << 12];             // 4KB per wave
        int8_t* dB = &lds[s][16384 + (wave << 11)];   // 2KB per wave
#pragma unroll
        for (int l = 0; l < 4; ++l)
            GLOAD_LDS16(Ag + ko + (size_t)(l * 16) * K, dA + (l << 10));
#pragma unroll
        for (int l = 0; l < 2; ++l)
            GLOAD_LDS16(Bg + ko + (size_t)(l * 16) * K, dB + (l << 10));
    };

    // ---- frag read offsets (i8 16x16x64: row = lane&15, chunk = lane>>4)
    const int fc   = (((lane >> 4) ^ ((lane >> 1) & 3)) << 4);    // swizzled chunk
    const int aoff = ((wm * 128 + (lane & 15)) << 6) + fc;        // + i*1024, i=0..7
    const int boff = 16384 + ((wn * 64 + (lane & 15)) << 6) + fc; // + j*1024

    v4i acc[8][4] = {};

    // prologue: 2 tiles in flight; counted wait for tile 0, cross-wave barrier
    stage(0, 0);
    stage(1, 1);
    VMC6();
    sbar();

    int sb = 0;
    for (int t = 0; t < NT; ++t) {
        const int8_t* base = &lds[sb][0];
        int s2 = sb + 2; if (s2 >= 3) s2 -= 3;

        // ---- phase 0: rows 0-63 of wave tile; bf loaded once, kept in regs
        v4i bf[4], af[4];
#pragma unroll
        for (int j = 0; j < 4; ++j)
            bf[j] = *reinterpret_cast<const v4i*>(base + boff + (j << 10));
#pragma unroll
        for (int i = 0; i < 4; ++i)
            af[i] = *reinterpret_cast<const v4i*>(base + aoff + (i << 10));
        if (t + 2 < NT) stage(s2, t + 2);

        __builtin_amdgcn_s_setprio(1);
#pragma unroll
        for (int i = 0; i < 4; ++i)
#pragma unroll
            for (int j = 0; j < 4; ++j)
                acc[i][j] = __builtin_amdgcn_mfma_i32_16x16x64_i8(af[i], bf[j], acc[i][j], 0, 0, 0);
        __builtin_amdgcn_s_setprio(0);

        // ---- phase 1: rows 64-127 (reuse af regs)
#pragma unroll
        for (int i = 0; i < 4; ++i)
            af[i] = *reinterpret_cast<const v4i*>(base + aoff + ((i + 4) << 10));

        __builtin_amdgcn_s_setprio(1);
#pragma unroll
        for (int i = 0; i < 4; ++i)
#pragma unroll
            for (int j = 0; j < 4; ++j)
                acc[i + 4][j] = __builtin_amdgcn_mfma_i32_16x16x64_i8(af[i], bf[j], acc[i + 4][j], 0, 0, 0);
        __builtin_amdgcn_s_setprio(0);

        if (t + 2 < NT)      VMC6();
        else if (t + 1 < NT) VMC0();
        sbar();
        if (++sb == 3) sb = 0;
    }

    // ---------------- epilogue ----------------
    const int quad = lane >> 4;
    const int col  = lane & 15;
#pragma unroll
    for (int i = 0; i < 8; ++i) {
#pragma unroll
        for (int r = 0; r < 4; ++r) {
            int m = mbase + (wm << 7) + (i << 4) + (quad << 2) + r;  // row=(lane>>4)*4+reg
            float rs = rowdq[m] * wdq;
#pragma unroll
            for (int j = 0; j < 4; ++j) {
                int n = nbase + (wn << 6) + (j << 4) + col;          // col=lane&15
                C[(size_t)m * N + n] = (OutT)((float)acc[i][j][r] * rs);
            }
        }
    }
}

// ---------------------------------------------------------------------------
// GEMM2 kernel (grid-constrained by N=1024): BM=128/BN=128, 4 waves, BK=64,
// 3-deep ring, one barrier per tile, counted vmcnt. Structure unchanged since
// r3 (never entered top-5). Only instantiated with WAVES=4 (256 threads --
// scale_pair requires this).
template <int BM, int WAVES, typename OutT>
__global__ __launch_bounds__(WAVES * 64, (BM == 256) ? 4 : 3)
void gemm_i8_bk64(const int8_t* __restrict__ A, const int8_t* __restrict__ Bm,
                  OutT* __restrict__ C, const float* __restrict__ rowdq,
                  const double* __restrict__ part, int widx, int N, int K) {
    constexpr int BN = 128;
    constexpr int ABYTES = BM * 64;           // A bytes per ring buffer
    constexpr int BUF = (BM + BN) * 64;       // bytes per ring buffer
    constexpr int ALOADS = BM / 16 / WAVES;   // per-wave 1KB A loads per tile
    constexpr int BLOADS = BN / 16 / WAVES;   // per-wave 1KB B loads per tile
    constexpr int L = ALOADS + BLOADS;        // per-wave loads per tile

    __shared__ __align__(16) int8_t lds[3][BUF];
    __shared__ double sred[256];
    const int tid  = threadIdx.x;
    const int lane = tid & 63;
    const int wave = tid >> 6;

    const float wdq = scale_pair(part, widx, sred).y;

    // XCD-chunked bijective swizzle (grid is a multiple of 8)
    const int nwg = gridDim.x * gridDim.y;
    int flat = blockIdx.y * gridDim.x + blockIdx.x;
    flat = (flat & 7) * (nwg >> 3) + (flat >> 3);
    const int bx = flat % gridDim.x;
    const int by = flat / gridDim.x;
    const int mbase = by * BM;
    const int nbase = bx << 7;
    const int NT = K >> 6;

    const int wm = wave >> 1;                 // m 64-row slab
    const int wn = wave & 1;                  // n 64-col half

    // ---- staging source addressing (inverse swizzle on global side)
    const int srow = lane >> 2;                               // row within 1KB load
    const int csrc = (((lane & 3) ^ ((lane >> 3) & 3)) << 4); // logical 16B chunk
    const int8_t* Ag = A  + (size_t)(mbase + wave * (ALOADS * 16) + srow) * K + csrc;
    const int8_t* Bg = Bm + (size_t)(nbase + wave * (BLOADS * 16) + srow) * K + csrc;

    auto stage = [&](int s, int tt) {
        const size_t ko = (size_t)tt << 6;
        int8_t* dA = &lds[s][(wave * ALOADS) << 10];
        int8_t* dB = &lds[s][ABYTES + ((wave * BLOADS) << 10)];
#pragma unroll
        for (int l = 0; l < ALOADS; ++l)
            GLOAD_LDS16(Ag + ko + (size_t)(l * 16) * K, dA + (l << 10));
#pragma unroll
        for (int l = 0; l < BLOADS; ++l)
            GLOAD_LDS16(Bg + ko + (size_t)(l * 16) * K, dB + (l << 10));
    };

    // ---- frag read offsets (i8 16x16x64: row = lane&15, chunk = lane>>4)
    const int fc   = (((lane >> 4) ^ ((lane >> 1) & 3)) << 4);  // swizzled chunk
    const int aoff = ((wm * 64 + (lane & 15)) << 6) + fc;       // + i*1024
    const int boff = ABYTES + ((wn * 64 + (lane & 15)) << 6) + fc;

    v4i acc[4][4] = {};

    // prologue: 2 tiles in flight; wait tile 0 (counted), cross-wave via barrier
    stage(0, 0);
    stage(1, 1);
    if constexpr (L == 3) VMC3(); else VMC4();
    sbar();

    int sb = 0;
    for (int t = 0; t < NT; ++t) {
        const int8_t* base = &lds[sb][0];
        v4i af[4], bf[4];
#pragma unroll
        for (int i = 0; i < 4; ++i)
            af[i] = *reinterpret_cast<const v4i*>(base + aoff + (i << 10));
#pragma unroll
        for (int j = 0; j < 4; ++j)
            bf[j] = *reinterpret_cast<const v4i*>(base + boff + (j << 10));
        int s2 = sb + 2; if (s2 >= 3) s2 -= 3;
        if (t + 2 < NT) stage(s2, t + 2);

        __builtin_amdgcn_s_setprio(1);
#pragma unroll
        for (int i = 0; i < 4; ++i)
#pragma unroll
            for (int j = 0; j < 4; ++j)
                acc[i][j] = __builtin_amdgcn_mfma_i32_16x16x64_i8(af[i], bf[j], acc[i][j], 0, 0, 0);
        __builtin_amdgcn_s_setprio(0);

        if (t + 2 < NT)      { if constexpr (L == 3) VMC3(); else VMC4(); }
        else if (t + 1 < NT) VMC0();
        sbar();
        if (++sb == 3) sb = 0;
    }

    // ---------------- epilogue ----------------
    const int quad = lane >> 4;
    const int col  = lane & 15;
#pragma unroll
    for (int i = 0; i < 4; ++i) {
#pragma unroll
        for (int r = 0; r < 4; ++r) {
            int m = mbase + (wm << 6) + (i << 4) + (quad << 2) + r;  // row=(lane>>4)*4+reg
            float rs = rowdq[m] * wdq;
#pragma unroll
            for (int j = 0; j < 4; ++j) {
                int n = nbase + (wn << 6) + (j << 4) + col;          // col=lane&15
                C[(size_t)m * N + n] = (OutT)((float)acc[i][j][r] * rs);
            }
        }
    }
}

// ---------------------------------------------------------------------------
extern "C" void kernel_launch(void* const* d_in, const int* in_sizes, int n_in,
                              void* d_out, int out_size, void* d_ws, size_t ws_size,
                              hipStream_t stream) {
    const float* x  = (const float*)d_in[0];  // [4,2048,1024]
    const float* w1 = (const float*)d_in[1];  // [4096,1024]
    const float* cw = (const float*)d_in[2];  // [4096,1,3]
    const float* cb = (const float*)d_in[3];  // [4096]
    const float* w2 = (const float*)d_in[4];  // [1024,4096]
    float* out = (float*)d_out;               // [4,2048,1024]
    char* ws = (char*)d_ws;

    // Workspace layout (16B-aligned)
    double* part  = (double*)(ws + 0);          // 2048 doubles
    float*  dqx   = (float*)(ws + 16640);       // 8192 floats
    float*  dqh   = (float*)(ws + 49408);       // 8192 floats
    int8_t* qw1   = (int8_t*)(ws + 82176);      // 4 MB
    int8_t* qw2   = (int8_t*)(ws + 4276480);    // 4 MB
    int8_t* qx    = (int8_t*)(ws + 8470784);    // 8 MB
    int8_t* qh    = (int8_t*)(ws + 16859392);   // 32 MB
    _Float16* h   = (_Float16*)(ws + 50413824); // 64 MB (fp16)

    absmean_partial<<<2048, 256, 0, stream>>>((const float4*)w1, (const float4*)w2, part);
    quant_all<<<16384, 256, 0, stream>>>((const float4*)w1, (const float4*)w2,
                                         (const float4*)x, (char4*)qw1, (char4*)qw2,
                                         (char4*)qx, dqx, part);

    // GEMM1: M=8192, N=4096, K=1024 -> h (fp16); 1024 blocks, 2 blocks/CU
    dim3 g1(DH / 128, NTOK / 256);
    gemm_i8_w128<_Float16><<<g1, 256, 0, stream>>>(qx, qw1, h, dqx, part, 0, DH, DM);

    conv_silu_quant<<<NTOK / CT, 512, 0, stream>>>((const half8*)h, (const float4*)cw,
                                                   (const float4*)cb, (char8v*)qh, dqh);

    // GEMM2: M=8192, N=1024, K=4096 -> out (fp32); 512 blocks, 3 blocks/CU
    dim3 g2(DM / 128, NTOK / 128);
    gemm_i8_bk64<128, 4, float><<<g2, 256, 0, stream>>>(qh, qw2, out, dqh, part, 1, DM, DH);
}

// Round 11
// 230.131 us; speedup vs baseline: 1.0655x; 1.0178x over previous
//
#include <hip/hip_runtime.h>
#include <cstdint>

// Problem sizes (fixed by reference)
#define S_    2048
#define DM    1024
#define DH    4096
#define NTOK  8192     // B*S = 4*2048
#define WELEM 4194304  // 4096*1024 elements in each weight matrix
#define CT    8        // tokens per conv block

typedef int v4i __attribute__((ext_vector_type(4)));
typedef _Float16 half8 __attribute__((ext_vector_type(8)));
typedef char char8v __attribute__((ext_vector_type(8)));

// async global->LDS, 16B per lane, dest = wave-uniform base (+ lane*16 by HW)
#define GLOAD_LDS16(g, l)                                                   \
    __builtin_amdgcn_global_load_lds(                                       \
        (const __attribute__((address_space(1))) void*)(g),                 \
        (__attribute__((address_space(3))) void*)(l), 16, 0, 0)

// raw barrier (no implicit vmcnt(0) drain) + compiler memory fence
static __device__ __forceinline__ void sbar() {
    asm volatile("" ::: "memory");
    __builtin_amdgcn_s_barrier();
    asm volatile("" ::: "memory");
}
#define VMC0() asm volatile("s_waitcnt vmcnt(0)" ::: "memory")
#define VMC3() asm volatile("s_waitcnt vmcnt(3)" ::: "memory")
#define VMC4() asm volatile("s_waitcnt vmcnt(4)" ::: "memory")
#define VMC6() asm volatile("s_waitcnt vmcnt(6)" ::: "memory")

// ---------------------------------------------------------------------------
// Per-block partial sums of |w| in fp64, both matrices in one launch.
__global__ __launch_bounds__(256) void absmean_partial(const float4* __restrict__ wa,
                                                       const float4* __restrict__ wb,
                                                       double* __restrict__ partial) {
    __shared__ double red[256];
    const float4* w = (blockIdx.x < 1024) ? wa : wb;
    int base = (blockIdx.x & 1023) * 1024;  // in float4 units
    double s = 0.0;
#pragma unroll
    for (int k = 0; k < 4; ++k) {
        float4 v = w[base + (k << 8) + threadIdx.x];
        s += (double)fabsf(v.x) + (double)fabsf(v.y) +
             (double)fabsf(v.z) + (double)fabsf(v.w);
    }
    red[threadIdx.x] = s;
    __syncthreads();
    for (int off = 128; off > 0; off >>= 1) {
        if (threadIdx.x < off) red[threadIdx.x] += red[threadIdx.x + off];
        __syncthreads();
    }
    if (threadIdx.x == 0) partial[blockIdx.x] = red[0];
}

// ---------------------------------------------------------------------------
// Deterministic recompute of {scale, 1/scale} from the 1024 fp64 partials of
// matrix m (0=w1, 1=w2). REQUIRES 256-thread blocks. Every calling block
// performs the identical IEEE op sequence -> bit-identical scale everywhere.
// Used ONLY inside quant_all (weight blocks need it anyway); the GEMMs read
// the value from sc[] written by quant_all's designated blocks -- r10 put
// this tree in the GEMM prologues and paid +5.5us on GEMM1 for it.
__device__ __forceinline__ float2 scale_pair(const double* __restrict__ part, int m,
                                             double* red) {
    const double* p = part + (m << 10);
    const int t = threadIdx.x;
    double s = p[t] + p[t + 256] + p[t + 512] + p[t + 768];
    red[t] = s;
    __syncthreads();
    for (int off = 128; off > 0; off >>= 1) {
        if (t < off) red[t] += red[t + off];
        __syncthreads();
    }
    double mean = red[0] / (double)WELEM;
    float mf = fmaxf((float)mean, 1e-5f);
    float scale = 1.0f / mf;
    float2 r; r.x = scale; r.y = 1.0f / scale;
    return r;
}

// One launch: blocks [0,8192) ternary-quantize w1/w2 (recomputing the scale
// deterministically per block); [8192,16384) int8-quantize x. Blocks 0 and
// 4096 additionally publish {scale, 1/scale} to sc[] for the GEMMs
// (stream-ordered after this kernel -> safe).
__global__ __launch_bounds__(256) void quant_all(const float4* __restrict__ w1,
                                                 const float4* __restrict__ w2,
                                                 const float4* __restrict__ x,
                                                 char4* __restrict__ qw1,
                                                 char4* __restrict__ qw2,
                                                 char4* __restrict__ qx,
                                                 float* __restrict__ dqx,
                                                 const double* __restrict__ part,
                                                 float* __restrict__ sc) {
    __shared__ double redd[256];
    __shared__ float  redf[256];
    if (blockIdx.x < 8192) {
        bool second = blockIdx.x >= 4096;
        const float4* w = second ? w2 : w1;
        char4* q = second ? qw2 : qw1;
        float2 sp = scale_pair(part, second ? 1 : 0, redd);
        float scale = sp.x;
        if ((blockIdx.x == 0 || blockIdx.x == 4096) && threadIdx.x == 0) {
            sc[second ? 2 : 0] = sp.x;
            sc[second ? 3 : 1] = sp.y;
        }
        int i = (blockIdx.x & 4095) * 256 + threadIdx.x;
        float4 v = w[i];
        char4 o;
        o.x = (signed char)(int)fminf(fmaxf(rintf(v.x * scale), -1.f), 1.f);
        o.y = (signed char)(int)fminf(fmaxf(rintf(v.y * scale), -1.f), 1.f);
        o.z = (signed char)(int)fminf(fmaxf(rintf(v.z * scale), -1.f), 1.f);
        o.w = (signed char)(int)fminf(fmaxf(rintf(v.w * scale), -1.f), 1.f);
        q[i] = o;
    } else {
        int t = blockIdx.x - 8192;
        float4 v = x[(size_t)t * 256 + threadIdx.x];
        float mx = fmaxf(fmaxf(fabsf(v.x), fabsf(v.y)), fmaxf(fabsf(v.z), fabsf(v.w)));
        redf[threadIdx.x] = mx;
        __syncthreads();
        for (int off = 128; off > 0; off >>= 1) {
            if (threadIdx.x < off) redf[threadIdx.x] = fmaxf(redf[threadIdx.x], redf[threadIdx.x + off]);
            __syncthreads();
        }
        float scale = 127.0f / fmaxf(redf[0], 1e-5f);
        // |v|*scale <= 127 by construction -> clamps redundant
        char4 o;
        o.x = (signed char)(int)rintf(v.x * scale);
        o.y = (signed char)(int)rintf(v.y * scale);
        o.z = (signed char)(int)rintf(v.z * scale);
        o.w = (signed char)(int)rintf(v.w * scale);
        qx[(size_t)t * 256 + threadIdx.x] = o;
        if (threadIdx.x == 0) dqx[t] = 1.0f / scale;
    }
}

// Fused depthwise conv3 (+bias) + SiLU + per-token int8 quant over DH=4096.
// SiLU via v_exp_f32/v_rcp_f32; quant clamps dropped (|v*scale| <= 127 by
// construction of scale).
__global__ __launch_bounds__(512) void conv_silu_quant(const half8* __restrict__ h,
                                                       const float4* __restrict__ cwv,
                                                       const float4* __restrict__ cbv,
                                                       char8v* __restrict__ q,
                                                       float* __restrict__ dq) {
    __shared__ float red[2][8];
    const int tid = threadIdx.x;
    const int t0 = blockIdx.x * CT;
    const int s0 = t0 & (S_ - 1);      // CT | S_, block never straddles batches

    float wc[24], bs[8];
    {
        float4 tmp;
#pragma unroll
        for (int i = 0; i < 6; ++i) {
            tmp = cwv[tid * 6 + i];
            wc[4 * i] = tmp.x; wc[4 * i + 1] = tmp.y; wc[4 * i + 2] = tmp.z; wc[4 * i + 3] = tmp.w;
        }
        tmp = cbv[tid * 2];     bs[0] = tmp.x; bs[1] = tmp.y; bs[2] = tmp.z; bs[3] = tmp.w;
        tmp = cbv[tid * 2 + 1]; bs[4] = tmp.x; bs[5] = tmp.y; bs[6] = tmp.z; bs[7] = tmp.w;
    }

    auto ldrow = [&](int t, bool valid, float* dst) {
        if (valid) {
            half8 raw = h[(size_t)t * 512 + tid];
#pragma unroll
            for (int e = 0; e < 8; ++e) dst[e] = (float)raw[e];
        } else {
#pragma unroll
            for (int e = 0; e < 8; ++e) dst[e] = 0.f;
        }
    };

    float pv[8], cu[8], nx[8], pf[8];
    ldrow(t0 - 1, s0 > 0, pv);
    ldrow(t0, true, cu);
    ldrow(t0 + 1, true, nx);

#pragma unroll
    for (int i = 0; i < CT; ++i) {
        const int t = t0 + i;
        ldrow(t + 2, (s0 + i + 2) < S_, pf);

        float v[8];
        float mx = 0.f;
#pragma unroll
        for (int e = 0; e < 8; ++e) {
            float y = wc[3 * e] * pv[e] + wc[3 * e + 1] * cu[e] + wc[3 * e + 2] * nx[e] + bs[e];
            // silu(y) = y * sigmoid(y) = y * rcp(1 + 2^(-y*log2e))
            float ex = __builtin_amdgcn_exp2f(-1.44269504088896f * y);
            float r  = y * __builtin_amdgcn_rcpf(1.0f + ex);
            v[e] = r;
            mx = fmaxf(mx, fabsf(r));
        }
#pragma unroll
        for (int off = 32; off > 0; off >>= 1)
            mx = fmaxf(mx, __shfl_down(mx, off, 64));
        if ((tid & 63) == 0) red[i & 1][tid >> 6] = mx;
        __syncthreads();
        float rmax = red[i & 1][0];
#pragma unroll
        for (int w = 1; w < 8; ++w) rmax = fmaxf(rmax, red[i & 1][w]);
        float scale = 127.0f / fmaxf(rmax, 1e-5f);
        char8v o;
#pragma unroll
        for (int e = 0; e < 8; ++e)
            o[e] = (signed char)(int)rintf(v[e] * scale);
        q[(size_t)t * 512 + tid] = o;
        if (tid == 0) dq[t] = 1.0f / scale;
#pragma unroll
        for (int e = 0; e < 8; ++e) { pv[e] = cu[e]; cu[e] = nx[e]; nx[e] = pf[e]; }
    }
}

// ---------------------------------------------------------------------------
// GEMM1 kernel (r5 config, best measured: 49.1 us): 256x128 block tile, BK=64,
// 4 waves as 2(M)x2(N), wave-tile 128x64, acc[8][4]. 3-deep LDS ring
// (3 x 24KB), __launch_bounds__(256,2): 256 regs/wave, no spill; 2 blocks/CU,
// each SIMD hosts waves from two different blocks (cross-block overlap).
// Weight scale: single scalar read sc[slot] in the EPILOGUE (off the main
// loop's critical path -- r10's prologue recompute cost +5.5us).
//
// Protocol per K-tile (one barrier, counted vmcnt never 0 mid-loop):
//   bf[4]+af[0..3] ds_read | stage(t+2) | 16 mfma | af[4..7] ds_read |
//   16 mfma | vmcnt(6) | s_barrier
// Recycle safety: stage(t+2) overwrites the buffer last read at t-1; every
// wave's t-1 ds_reads retired before its t-1 MFMAs (register dependency),
// which precede barrier(t-1), which precedes stage(t+2).
// vmcnt(6): at the wait, 12 loads in flight (t+1's 6 + t+2's 6); retires
// t+1's. Barrier makes the per-wave guarantee cross-wave.
//
// Swizzle (64B LDS rows, verified conflict-free r2-r10): phys_chunk =
// chunk ^ ((row>>1)&3), involution on both staging source and ds_read.
template <typename OutT>
__global__ __launch_bounds__(256, 2)
void gemm_i8_w128(const int8_t* __restrict__ A, const int8_t* __restrict__ Bm,
                  OutT* __restrict__ C, const float* __restrict__ rowdq,
                  const float* __restrict__ sc, int slot, int N, int K) {
    __shared__ __align__(16) int8_t lds[3][24576];   // [buf][A 16KB | B 8KB]
    const int tid  = threadIdx.x;
    const int lane = tid & 63;
    const int wave = tid >> 6;

    // XCD-chunked bijective swizzle (grid is a multiple of 8)
    const int nwg = gridDim.x * gridDim.y;
    int flat = blockIdx.y * gridDim.x + blockIdx.x;
    flat = (flat & 7) * (nwg >> 3) + (flat >> 3);
    const int bx = flat % gridDim.x;
    const int by = flat / gridDim.x;
    const int mbase = by << 8;               // BM=256
    const int nbase = bx << 7;               // BN=128
    const int NT = K >> 6;

    const int wm = wave >> 1;                // 0..1  (128-row half)
    const int wn = wave & 1;                 // 0..1  (64-col half)

    // ---- staging source addressing (inverse swizzle on global side)
    // wave w stages A rows [64w,64w+64) (4 x 1KB) and B rows [32w,32w+32) (2 x 1KB)
    const int srow = lane >> 2;                               // row within 1KB unit
    const int csrc = (((lane & 3) ^ ((lane >> 3) & 3)) << 4); // logical 16B chunk
    const int8_t* Ag = A  + (size_t)(mbase + wave * 64 + srow) * K + csrc;
    const int8_t* Bg = Bm + (size_t)(nbase + wave * 32 + srow) * K + csrc;

    auto stage = [&](int s, int tt) {
        const size_t ko = (size_t)tt << 6;
        int8_t* dA = &lds[s][wave << 12];             // 4KB per wave
        int8_t* dB = &lds[s][16384 + (wave << 11)];   // 2KB per wave
#pragma unroll
        for (int l = 0; l < 4; ++l)
            GLOAD_LDS16(Ag + ko + (size_t)(l * 16) * K, dA + (l << 10));
#pragma unroll
        for (int l = 0; l < 2; ++l)
            GLOAD_LDS16(Bg + ko + (size_t)(l * 16) * K, dB + (l << 10));
    };

    // ---- frag read offsets (i8 16x16x64: row = lane&15, chunk = lane>>4)
    const int fc   = (((lane >> 4) ^ ((lane >> 1) & 3)) << 4);    // swizzled chunk
    const int aoff = ((wm * 128 + (lane & 15)) << 6) + fc;        // + i*1024, i=0..7
    const int boff = 16384 + ((wn * 64 + (lane & 15)) << 6) + fc; // + j*1024

    v4i acc[8][4] = {};

    // prologue: 2 tiles in flight; counted wait for tile 0, cross-wave barrier
    stage(0, 0);
    stage(1, 1);
    VMC6();
    sbar();

    int sb = 0;
    for (int t = 0; t < NT; ++t) {
        const int8_t* base = &lds[sb][0];
        int s2 = sb + 2; if (s2 >= 3) s2 -= 3;

        // ---- phase 0: rows 0-63 of wave tile; bf loaded once, kept in regs
        v4i bf[4], af[4];
#pragma unroll
        for (int j = 0; j < 4; ++j)
            bf[j] = *reinterpret_cast<const v4i*>(base + boff + (j << 10));
#pragma unroll
        for (int i = 0; i < 4; ++i)
            af[i] = *reinterpret_cast<const v4i*>(base + aoff + (i << 10));
        if (t + 2 < NT) stage(s2, t + 2);

        __builtin_amdgcn_s_setprio(1);
#pragma unroll
        for (int i = 0; i < 4; ++i)
#pragma unroll
            for (int j = 0; j < 4; ++j)
                acc[i][j] = __builtin_amdgcn_mfma_i32_16x16x64_i8(af[i], bf[j], acc[i][j], 0, 0, 0);
        __builtin_amdgcn_s_setprio(0);

        // ---- phase 1: rows 64-127 (reuse af regs)
#pragma unroll
        for (int i = 0; i < 4; ++i)
            af[i] = *reinterpret_cast<const v4i*>(base + aoff + ((i + 4) << 10));

        __builtin_amdgcn_s_setprio(1);
#pragma unroll
        for (int i = 0; i < 4; ++i)
#pragma unroll
            for (int j = 0; j < 4; ++j)
                acc[i + 4][j] = __builtin_amdgcn_mfma_i32_16x16x64_i8(af[i], bf[j], acc[i + 4][j], 0, 0, 0);
        __builtin_amdgcn_s_setprio(0);

        if (t + 2 < NT)      VMC6();
        else if (t + 1 < NT) VMC0();
        sbar();
        if (++sb == 3) sb = 0;
    }

    // ---------------- epilogue ----------------
    const float wdq = sc[slot];
    const int quad = lane >> 4;
    const int col  = lane & 15;
#pragma unroll
    for (int i = 0; i < 8; ++i) {
#pragma unroll
        for (int r = 0; r < 4; ++r) {
            int m = mbase + (wm << 7) + (i << 4) + (quad << 2) + r;  // row=(lane>>4)*4+reg
            float rs = rowdq[m] * wdq;
#pragma unroll
            for (int j = 0; j < 4; ++j) {
                int n = nbase + (wn << 6) + (j << 4) + col;          // col=lane&15
                C[(size_t)m * N + n] = (OutT)((float)acc[i][j][r] * rs);
            }
        }
    }
}

// ---------------------------------------------------------------------------
// GEMM2 kernel (grid-constrained by N=1024): BM=128/BN=128, 4 waves, BK=64,
// 3-deep ring, one barrier per tile, counted vmcnt. Scale via sc[slot]
// scalar read in the epilogue (r5/r9 form).
template <int BM, int WAVES, typename OutT>
__global__ __launch_bounds__(WAVES * 64, (BM == 256) ? 4 : 3)
void gemm_i8_bk64(const int8_t* __restrict__ A, const int8_t* __restrict__ Bm,
                  OutT* __restrict__ C, const float* __restrict__ rowdq,
                  const float* __restrict__ sc, int slot, int N, int K) {
    constexpr int BN = 128;
    constexpr int ABYTES = BM * 64;           // A bytes per ring buffer
    constexpr int BUF = (BM + BN) * 64;       // bytes per ring buffer
    constexpr int ALOADS = BM / 16 / WAVES;   // per-wave 1KB A loads per tile
    constexpr int BLOADS = BN / 16 / WAVES;   // per-wave 1KB B loads per tile
    constexpr int L = ALOADS + BLOADS;        // per-wave loads per tile

    __shared__ __align__(16) int8_t lds[3][BUF];
    const int tid  = threadIdx.x;
    const int lane = tid & 63;
    const int wave = tid >> 6;

    // XCD-chunked bijective swizzle (grid is a multiple of 8)
    const int nwg = gridDim.x * gridDim.y;
    int flat = blockIdx.y * gridDim.x + blockIdx.x;
    flat = (flat & 7) * (nwg >> 3) + (flat >> 3);
    const int bx = flat % gridDim.x;
    const int by = flat / gridDim.x;
    const int mbase = by * BM;
    const int nbase = bx << 7;
    const int NT = K >> 6;

    const int wm = wave >> 1;                 // m 64-row slab
    const int wn = wave & 1;                  // n 64-col half

    // ---- staging source addressing (inverse swizzle on global side)
    const int srow = lane >> 2;                               // row within 1KB load
    const int csrc = (((lane & 3) ^ ((lane >> 3) & 3)) << 4); // logical 16B chunk
    const int8_t* Ag = A  + (size_t)(mbase + wave * (ALOADS * 16) + srow) * K + csrc;
    const int8_t* Bg = Bm + (size_t)(nbase + wave * (BLOADS * 16) + srow) * K + csrc;

    auto stage = [&](int s, int tt) {
        const size_t ko = (size_t)tt << 6;
        int8_t* dA = &lds[s][(wave * ALOADS) << 10];
        int8_t* dB = &lds[s][ABYTES + ((wave * BLOADS) << 10)];
#pragma unroll
        for (int l = 0; l < ALOADS; ++l)
            GLOAD_LDS16(Ag + ko + (size_t)(l * 16) * K, dA + (l << 10));
#pragma unroll
        for (int l = 0; l < BLOADS; ++l)
            GLOAD_LDS16(Bg + ko + (size_t)(l * 16) * K, dB + (l << 10));
    };

    // ---- frag read offsets (i8 16x16x64: row = lane&15, chunk = lane>>4)
    const int fc   = (((lane >> 4) ^ ((lane >> 1) & 3)) << 4);  // swizzled chunk
    const int aoff = ((wm * 64 + (lane & 15)) << 6) + fc;       // + i*1024
    const int boff = ABYTES + ((wn * 64 + (lane & 15)) << 6) + fc;

    v4i acc[4][4] = {};

    // prologue: 2 tiles in flight; wait tile 0 (counted), cross-wave via barrier
    stage(0, 0);
    stage(1, 1);
    if constexpr (L == 3) VMC3(); else VMC4();
    sbar();

    int sb = 0;
    for (int t = 0; t < NT; ++t) {
        const int8_t* base = &lds[sb][0];
        v4i af[4], bf[4];
#pragma unroll
        for (int i = 0; i < 4; ++i)
            af[i] = *reinterpret_cast<const v4i*>(base + aoff + (i << 10));
#pragma unroll
        for (int j = 0; j < 4; ++j)
            bf[j] = *reinterpret_cast<const v4i*>(base + boff + (j << 10));
        int s2 = sb + 2; if (s2 >= 3) s2 -= 3;
        if (t + 2 < NT) stage(s2, t + 2);

        __builtin_amdgcn_s_setprio(1);
#pragma unroll
        for (int i = 0; i < 4; ++i)
#pragma unroll
            for (int j = 0; j < 4; ++j)
                acc[i][j] = __builtin_amdgcn_mfma_i32_16x16x64_i8(af[i], bf[j], acc[i][j], 0, 0, 0);
        __builtin_amdgcn_s_setprio(0);

        if (t + 2 < NT)      { if constexpr (L == 3) VMC3(); else VMC4(); }
        else if (t + 1 < NT) VMC0();
        sbar();
        if (++sb == 3) sb = 0;
    }

    // ---------------- epilogue ----------------
    const float wdq = sc[slot];
    const int quad = lane >> 4;
    const int col  = lane & 15;
#pragma unroll
    for (int i = 0; i < 4; ++i) {
#pragma unroll
        for (int r = 0; r < 4; ++r) {
            int m = mbase + (wm << 6) + (i << 4) + (quad << 2) + r;  // row=(lane>>4)*4+reg
            float rs = rowdq[m] * wdq;
#pragma unroll
            for (int j = 0; j < 4; ++j) {
                int n = nbase + (wn << 6) + (j << 4) + col;          // col=lane&15
                C[(size_t)m * N + n] = (OutT)((float)acc[i][j][r] * rs);
            }
        }
    }
}

// ---------------------------------------------------------------------------
extern "C" void kernel_launch(void* const* d_in, const int* in_sizes, int n_in,
                              void* d_out, int out_size, void* d_ws, size_t ws_size,
                              hipStream_t stream) {
    const float* x  = (const float*)d_in[0];  // [4,2048,1024]
    const float* w1 = (const float*)d_in[1];  // [4096,1024]
    const float* cw = (const float*)d_in[2];  // [4096,1,3]
    const float* cb = (const float*)d_in[3];  // [4096]
    const float* w2 = (const float*)d_in[4];  // [1024,4096]
    float* out = (float*)d_out;               // [4,2048,1024]
    char* ws = (char*)d_ws;

    // Workspace layout (16B-aligned)
    double* part  = (double*)(ws + 0);          // 2048 doubles
    float*  sc    = (float*)(ws + 16384);       // {scale_w1, dq_w1, scale_w2, dq_w2}
    float*  dqx   = (float*)(ws + 16640);       // 8192 floats
    float*  dqh   = (float*)(ws + 49408);       // 8192 floats
    int8_t* qw1   = (int8_t*)(ws + 82176);      // 4 MB
    int8_t* qw2   = (int8_t*)(ws + 4276480);    // 4 MB
    int8_t* qx    = (int8_t*)(ws + 8470784);    // 8 MB
    int8_t* qh    = (int8_t*)(ws + 16859392);   // 32 MB
    _Float16* h   = (_Float16*)(ws + 50413824); // 64 MB (fp16)

    absmean_partial<<<2048, 256, 0, stream>>>((const float4*)w1, (const float4*)w2, part);
    quant_all<<<16384, 256, 0, stream>>>((const float4*)w1, (const float4*)w2,
                                         (const float4*)x, (char4*)qw1, (char4*)qw2,
                                         (char4*)qx, dqx, part, sc);

    // GEMM1: M=8192, N=4096, K=1024 -> h (fp16); 1024 blocks, 2 blocks/CU
    dim3 g1(DH / 128, NTOK / 256);
    gemm_i8_w128<_Float16><<<g1, 256, 0, stream>>>(qx, qw1, h, dqx, sc, 1, DH, DM);

    conv_silu_quant<<<NTOK / CT, 512, 0, stream>>>((const half8*)h, (const float4*)cw,
                                                   (const float4*)cb, (char8v*)qh, dqh);

    // GEMM2: M=8192, N=1024, K=4096 -> out (fp32); 512 blocks
    dim3 g2(DM / 128, NTOK / 128);
    gemm_i8_bk64<128, 4, float><<<g2, 256, 0, stream>>>(qh, qw2, out, dqh, sc, 3, DM, DH);
}